// Round 7
// baseline (800.009 us; speedup 1.0000x reference)
//
#include <hip/hip_runtime.h>
#include <hip/hip_bf16.h>
#include <math.h>

// ---------------------------------------------------------------------------
// Transformer block. R6:
//  - GEMM K-loop: BK=64, single LDS buffer, reg-staged (plain global loads),
//    2 barriers per 64-K iter -> 32 MFMA per barrier-pair (AITER signature).
//    LDS rows strided 144 B (2-way-max bank aliasing everywhere = free).
//    XCD-compact swizzle kept (R5: fixed FETCH 143->41 MB).
//  - LN kernels vectorized (float4 / bf16x8).
//  - GELU in sigmoid form (|diff| <= ~1e-3, halves epilogue VALU).
//  - Attention: R5 pipelined MFMA flash kernel (unchanged).
// ---------------------------------------------------------------------------

#define TOKENS 4096
#define CDIM   1024
#define HEADS  16
#define DHEAD  64
#define HID    4096

typedef __attribute__((ext_vector_type(4))) float  floatx4;
typedef __attribute__((ext_vector_type(8))) short  short8;  // 8 x bf16 frag

// ---------------- fused fp32 -> bf16 weight convert ----------------
__global__ __launch_bounds__(256) void cvt_all(
    const float* __restrict__ s0, const float* __restrict__ s1,
    const float* __restrict__ s2, const float* __restrict__ s3,
    __hip_bfloat16* __restrict__ dst)
{
    long i = (long)blockIdx.x * 256 + threadIdx.x;   // float4 index, 3M total
    const float* src;
    long base;
    if (i < 768l * 1024)       { src = s0; base = 0; }
    else if (i < 1792l * 1024) { src = s1; base = 768l * 1024; }
    else if (i < 2816l * 1024) { src = s2; base = 1792l * 1024; }
    else                       { src = s3; base = 2816l * 1024; }
    float4 v = ((const float4*)src)[i - base];
    __hip_bfloat16 t[4];
    t[0] = __float2bfloat16(v.x);
    t[1] = __float2bfloat16(v.y);
    t[2] = __float2bfloat16(v.z);
    t[3] = __float2bfloat16(v.w);
    *(uint2*)(dst + 4l * i) = *(uint2*)t;
}

// ---------------- LayerNorm: fp32 in -> bf16 out (vectorized) --------------
__global__ __launch_bounds__(256) void ln_f32_kernel(
    const float* __restrict__ x, const float* __restrict__ g,
    const float* __restrict__ b, __hip_bfloat16* __restrict__ y, int C)
{
    int row = blockIdx.x;
    const float4* xr = (const float4*)(x + (long)row * C);
    uint2* yr = (uint2*)(y + (long)row * C);
    const int C4 = C >> 2;

    float s = 0.f, ss = 0.f;
    for (int i = threadIdx.x; i < C4; i += 256) {
        float4 v = xr[i];
        s  += v.x + v.y + v.z + v.w;
        ss += v.x * v.x + v.y * v.y + v.z * v.z + v.w * v.w;
    }
    #pragma unroll
    for (int d = 32; d; d >>= 1) {
        s  += __shfl_down(s, d);
        ss += __shfl_down(ss, d);
    }
    __shared__ float buf[4][2];
    int wid = threadIdx.x >> 6, lane = threadIdx.x & 63;
    if (lane == 0) { buf[wid][0] = s; buf[wid][1] = ss; }
    __syncthreads();
    if (threadIdx.x == 0) {
        s = buf[0][0] + buf[1][0] + buf[2][0] + buf[3][0];
        ss = buf[0][1] + buf[1][1] + buf[2][1] + buf[3][1];
        buf[0][0] = s; buf[0][1] = ss;
    }
    __syncthreads();
    s = buf[0][0]; ss = buf[0][1];

    float invC = 1.f / (float)C;
    float mu = s * invC;
    float var = ss * invC - mu * mu;
    float inv = rsqrtf(var + 1e-5f);
    const float4* gg = (const float4*)g;
    const float4* bb = (const float4*)b;
    for (int i = threadIdx.x; i < C4; i += 256) {
        float4 v = xr[i], gv = gg[i], bv = bb[i];
        __hip_bfloat16 t[4];
        t[0] = __float2bfloat16((v.x - mu) * inv * gv.x + bv.x);
        t[1] = __float2bfloat16((v.y - mu) * inv * gv.y + bv.y);
        t[2] = __float2bfloat16((v.z - mu) * inv * gv.z + bv.z);
        t[3] = __float2bfloat16((v.w - mu) * inv * gv.w + bv.w);
        yr[i] = *(uint2*)t;
    }
}

// ---------------- LayerNorm: bf16 in -> bf16 out (vectorized, in place ok) --
__global__ __launch_bounds__(256) void ln_bf16_kernel(
    const __hip_bfloat16* __restrict__ x, const float* __restrict__ g,
    const float* __restrict__ b, __hip_bfloat16* __restrict__ y, int C)
{
    int row = blockIdx.x;
    const uint4* xr = (const uint4*)(x + (long)row * C);
    uint4* yr = (uint4*)(y + (long)row * C);
    const int C8 = C >> 3;

    float s = 0.f, ss = 0.f;
    for (int i = threadIdx.x; i < C8; i += 256) {
        uint4 raw = xr[i];
        const __hip_bfloat16* p = (const __hip_bfloat16*)&raw;
        #pragma unroll
        for (int j = 0; j < 8; ++j) {
            float v = __bfloat162float(p[j]);
            s += v; ss += v * v;
        }
    }
    #pragma unroll
    for (int d = 32; d; d >>= 1) {
        s  += __shfl_down(s, d);
        ss += __shfl_down(ss, d);
    }
    __shared__ float buf[4][2];
    int wid = threadIdx.x >> 6, lane = threadIdx.x & 63;
    if (lane == 0) { buf[wid][0] = s; buf[wid][1] = ss; }
    __syncthreads();
    if (threadIdx.x == 0) {
        s = buf[0][0] + buf[1][0] + buf[2][0] + buf[3][0];
        ss = buf[0][1] + buf[1][1] + buf[2][1] + buf[3][1];
        buf[0][0] = s; buf[0][1] = ss;
    }
    __syncthreads();
    s = buf[0][0]; ss = buf[0][1];

    float invC = 1.f / (float)C;
    float mu = s * invC;
    float var = ss * invC - mu * mu;
    float inv = rsqrtf(var + 1e-5f);
    const float4* gg = (const float4*)g;
    const float4* bb = (const float4*)b;
    for (int i = threadIdx.x; i < C8; i += 256) {
        uint4 raw = xr[i];
        const __hip_bfloat16* p = (const __hip_bfloat16*)&raw;
        float4 g0 = gg[2 * i], g1 = gg[2 * i + 1];
        float4 b0 = bb[2 * i], b1 = bb[2 * i + 1];
        __hip_bfloat16 t[8];
        t[0] = __float2bfloat16((__bfloat162float(p[0]) - mu) * inv * g0.x + b0.x);
        t[1] = __float2bfloat16((__bfloat162float(p[1]) - mu) * inv * g0.y + b0.y);
        t[2] = __float2bfloat16((__bfloat162float(p[2]) - mu) * inv * g0.z + b0.z);
        t[3] = __float2bfloat16((__bfloat162float(p[3]) - mu) * inv * g0.w + b0.w);
        t[4] = __float2bfloat16((__bfloat162float(p[4]) - mu) * inv * g1.x + b1.x);
        t[5] = __float2bfloat16((__bfloat162float(p[5]) - mu) * inv * g1.y + b1.y);
        t[6] = __float2bfloat16((__bfloat162float(p[6]) - mu) * inv * g1.z + b1.z);
        t[7] = __float2bfloat16((__bfloat162float(p[7]) - mu) * inv * g1.w + b1.w);
        yr[i] = *(uint4*)t;
    }
}

// ---------------- bf16 MFMA GEMM, BK=64 single-buffer, 32 MFMA/barrier -----
// C = A[M,K] @ W[N,K]^T (+bias)(+gelu)(+residual)
// Tile 128 x TN, BK=64, 256 threads = 4 waves.
// LDS row stride = 144 B (72 bf16): staging writes, frag b128 reads all
// <=2-way bank aliasing (free per m136).
#define LSTR 144
template <int TN>
__global__ __launch_bounds__(256, 3) void gemm_mfma(
    const __hip_bfloat16* __restrict__ A,
    const __hip_bfloat16* __restrict__ W,
    const float* __restrict__ bias, const float* __restrict__ residual,
    void* __restrict__ Cout, int M, int N, int K, int act, int out_bf16)
{
    constexpr int WN = (TN == 128) ? 2 : 1;
    constexpr int WM = 4 / WN;              // 2 or 4
    constexpr int FJ = 4;
    constexpr int FI = 128 / (WM * 16);     // 4 or 2
    constexpr int BCH = (TN == 128) ? 4 : 2;  // B 16B-chunks per thread

    __shared__ __align__(16) char Asl[128 * LSTR];   // 18 KB
    __shared__ __align__(16) char Bsl[TN * LSTR];    // 18 / 9 KB

    int tid = threadIdx.x;
    int wave = tid >> 6, lane = tid & 63;

    // XCD-compact swizzle: XCD = lin % 8 owns a contiguous M-tile band.
    int mt, nt;
    {
        int gx = gridDim.x, gy = gridDim.y;
        int lin = blockIdx.y * gx + blockIdx.x;
        if ((gy & 7) == 0) {
            int chunk = gy >> 3;
            int xcd = lin & 7, q = lin >> 3;
            mt = xcd * chunk + (q % chunk);
            nt = q / chunk;
        } else { mt = blockIdx.y; nt = blockIdx.x; }
    }
    int bm = mt * 128, bn = nt * TN;
    int wm = wave & (WM - 1), wn = wave / WM;
    int fm = lane & 15, quad = lane >> 4;

    // staging: 16B chunk cc = tid + 256*i -> row = cc>>3 (step 32), col = cc&7
    int r0 = tid >> 3;             // 0..31
    int col = tid & 7;             // 16B column within 64-elem row
    const __hip_bfloat16* ApG = A + (long)(bm + r0) * K + col * 8;
    const __hip_bfloat16* BpG = W + (long)(bn + r0) * K + col * 8;
    const long r32 = (long)32 * K;
    const int lo = r0 * LSTR + col * 16;

    uint4 ar[4], br[BCH];

    auto gload = [&](int t) {
        const long o = (long)t * 64;
        ar[0] = *(const uint4*)(ApG + o);
        ar[1] = *(const uint4*)(ApG + r32 + o);
        ar[2] = *(const uint4*)(ApG + 2 * r32 + o);
        ar[3] = *(const uint4*)(ApG + 3 * r32 + o);
        br[0] = *(const uint4*)(BpG + o);
        br[1] = *(const uint4*)(BpG + r32 + o);
        if (BCH == 4) {
            br[2] = *(const uint4*)(BpG + 2 * r32 + o);
            br[3] = *(const uint4*)(BpG + 3 * r32 + o);
        }
    };
    auto lwrite = [&]() {
        *(uint4*)(Asl + lo)              = ar[0];
        *(uint4*)(Asl + lo + 32 * LSTR)  = ar[1];
        *(uint4*)(Asl + lo + 64 * LSTR)  = ar[2];
        *(uint4*)(Asl + lo + 96 * LSTR)  = ar[3];
        *(uint4*)(Bsl + lo)              = br[0];
        *(uint4*)(Bsl + lo + 32 * LSTR)  = br[1];
        if (BCH == 4) {
            *(uint4*)(Bsl + lo + 64 * LSTR) = br[2];
            *(uint4*)(Bsl + lo + 96 * LSTR) = br[3];
        }
    };

    floatx4 acc[FI][FJ] = {};
    const int nk = K / 64;

    gload(0);
    for (int t = 0; t < nk; ++t) {
        __syncthreads();               // all waves done reading LDS tile t-1
        lwrite();                      // vmcnt waits on tile t's loads
        __syncthreads();               // tile t visible
        if (t + 1 < nk) gload(t + 1);  // in flight across the whole compute
        #pragma unroll
        for (int kh = 0; kh < 2; ++kh) {
            short8 bfr[FJ], af[FI];
            #pragma unroll
            for (int j = 0; j < FJ; ++j)
                bfr[j] = *(const short8*)(Bsl + (wn * 64 + j * 16 + fm) * LSTR
                                          + kh * 64 + quad * 16);
            #pragma unroll
            for (int i = 0; i < FI; ++i)
                af[i] = *(const short8*)(Asl + (wm * FI * 16 + i * 16 + fm) * LSTR
                                         + kh * 64 + quad * 16);
            #pragma unroll
            for (int i = 0; i < FI; ++i)
                #pragma unroll
                for (int j = 0; j < FJ; ++j)
                    acc[i][j] = __builtin_amdgcn_mfma_f32_16x16x32_bf16(
                        af[i], bfr[j], acc[i][j], 0, 0, 0);
        }
    }

    int mbase = bm + wm * FI * 16;
    int nbase = bn + wn * 64;
    #pragma unroll
    for (int i = 0; i < FI; ++i) {
        #pragma unroll
        for (int j = 0; j < FJ; ++j) {
            int ncol = nbase + j * 16 + fm;
            #pragma unroll
            for (int r = 0; r < 4; ++r) {
                int mrow = mbase + i * 16 + quad * 4 + r;
                float v = acc[i][j][r];
                if (bias) v += bias[ncol];
                if (act == 1) {
                    // gelu (tanh/sigmoid form): v * sigmoid(1.5957692*(v+0.044715 v^3))
                    float z = v * (1.5957691216f + 0.0713548162f * v * v);
                    v = v / (1.f + __expf(-z));
                }
                if (residual) v += residual[(long)mrow * N + ncol];
                if (out_bf16)
                    ((__hip_bfloat16*)Cout)[(long)mrow * N + ncol] = __float2bfloat16(v);
                else
                    ((float*)Cout)[(long)mrow * N + ncol] = v;
            }
        }
    }
}

// ---------------- MFMA flash attention, pipelined (R5, unchanged) ----------
__global__ __launch_bounds__(256) void attn_mfma(
    const __hip_bfloat16* __restrict__ qkv, __hip_bfloat16* __restrict__ o_out)
{
    __shared__ __align__(16) char Ks[2][64 * 144];
    __shared__ __align__(16) char Vt[2][64 * 144];
    __shared__ __align__(16) char Ps[4 * 16 * 144];

    const int C3 = 3 * CDIM;
    int lin = blockIdx.x;
    int xcd = lin & 7, q = lin >> 3;
    int bh = xcd * 8 + (q >> 4);
    int qt = q & 15;
    int b = bh >> 4, hh = bh & 15;
    int tid = threadIdx.x, wave = tid >> 6, lane = tid & 63;
    int l = lane & 15, quad = lane >> 4;

    const __hip_bfloat16* qrow =
        qkv + (long)(b * 1024 + qt * 64 + wave * 16 + l) * C3 + hh * DHEAD;
    short8 qf0 = *(const short8*)(qrow + quad * 8);
    short8 qf1 = *(const short8*)(qrow + 32 + quad * 8);

    char* Psw = Ps + wave * (16 * 144);

    int sc = tid & 7;
    int skl = tid >> 3;

    const __hip_bfloat16* Kbase = qkv + (long)(b * 1024) * C3 + CDIM + hh * DHEAD;
    const __hip_bfloat16* Vbase = qkv + (long)(b * 1024) * C3 + 2 * CDIM + hh * DHEAD;
    const int kpp = skl ^ (sc << 2);

    floatx4 facc[4] = {};
    float mrun = -1e30f, lrun = 0.f;

    uint4 kA0, kA1, vA0, vA1;
    uint4 kB0, kB1, vB0, vB1;

#define GKV(t, k0, k1, v0, v1) { \
    const __hip_bfloat16* Kg = Kbase + (long)((t) * 64) * C3; \
    const __hip_bfloat16* Vg = Vbase + (long)((t) * 64) * C3; \
    k0 = *(const uint4*)(Kg + (long)skl * C3 + sc * 8); \
    k1 = *(const uint4*)(Kg + (long)(skl + 32) * C3 + sc * 8); \
    v0 = *(const uint4*)(Vg + (long)(2 * skl) * C3 + sc * 8); \
    v1 = *(const uint4*)(Vg + (long)(2 * skl + 1) * C3 + sc * 8); }
#define WKV(bf, k0, k1, v0, v1) { \
    *(uint4*)(Ks[bf] + skl * 144 + sc * 16) = k0; \
    *(uint4*)(Ks[bf] + (skl + 32) * 144 + sc * 16) = k1; \
    const ushort* e0 = (const ushort*)&v0; \
    const ushort* e1 = (const ushort*)&v1; \
    _Pragma("unroll") \
    for (int j = 0; j < 8; ++j) { \
        unsigned dw = (unsigned)e0[j] | ((unsigned)e1[j] << 16); \
        *(unsigned*)(Vt[bf] + (sc * 8 + j) * 144 + kpp * 4) = dw; \
    } }

    auto compute = [&](int buf) {
        floatx4 st[4] = {};
        #pragma unroll
        for (int kb = 0; kb < 4; ++kb) {
            short8 k0 = *(const short8*)(Ks[buf] + (kb * 16 + l) * 144 + quad * 16);
            short8 k1 = *(const short8*)(Ks[buf] + (kb * 16 + l) * 144 + 64 + quad * 16);
            st[kb] = __builtin_amdgcn_mfma_f32_16x16x32_bf16(k0, qf0, st[kb], 0, 0, 0);
            st[kb] = __builtin_amdgcn_mfma_f32_16x16x32_bf16(k1, qf1, st[kb], 0, 0, 0);
        }
        float p[16];
        float tm = -1e30f;
        #pragma unroll
        for (int kb = 0; kb < 4; ++kb)
            #pragma unroll
            for (int r = 0; r < 4; ++r) {
                float s = st[kb][r] * 0.125f;
                p[kb * 4 + r] = s;
                tm = fmaxf(tm, s);
            }
        tm = fmaxf(tm, __shfl_xor(tm, 16));
        tm = fmaxf(tm, __shfl_xor(tm, 32));
        float mn = fmaxf(mrun, tm);
        float alpha = __expf(mrun - mn);
        float psum = 0.f;
        #pragma unroll
        for (int i = 0; i < 16; ++i) { p[i] = __expf(p[i] - mn); psum += p[i]; }
        psum += __shfl_xor(psum, 16);
        psum += __shfl_xor(psum, 32);
        lrun = lrun * alpha + psum;
        mrun = mn;

        #pragma unroll
        for (int kb = 0; kb < 4; ++kb) {
            __hip_bfloat16 t[4];
            #pragma unroll
            for (int r = 0; r < 4; ++r) t[r] = __float2bfloat16(p[kb * 4 + r]);
            *(uint2*)(Psw + l * 144 + kb * 32 + quad * 8) = *(const uint2*)t;
        }

        float a0 = __shfl(alpha, quad * 4 + 0);
        float a1 = __shfl(alpha, quad * 4 + 1);
        float a2 = __shfl(alpha, quad * 4 + 2);
        float a3 = __shfl(alpha, quad * 4 + 3);
        #pragma unroll
        for (int db = 0; db < 4; ++db) {
            facc[db][0] *= a0; facc[db][1] *= a1;
            facc[db][2] *= a2; facc[db][3] *= a3;
        }

        short8 pf0 = *(const short8*)(Psw + l * 144 + quad * 16);
        short8 pf1 = *(const short8*)(Psw + l * 144 + 64 + quad * 16);
        #pragma unroll
        for (int db = 0; db < 4; ++db) {
            int d = db * 16 + l;
            int o3 = (d >> 3) & 7;
            short8 v0 = *(const short8*)(Vt[buf] + d * 144 + ((quad ^ o3) << 4));
            short8 v1 = *(const short8*)(Vt[buf] + d * 144 + (((4 + quad) ^ o3) << 4));
            facc[db] = __builtin_amdgcn_mfma_f32_16x16x32_bf16(pf0, v0, facc[db], 0, 0, 0);
            facc[db] = __builtin_amdgcn_mfma_f32_16x16x32_bf16(pf1, v1, facc[db], 0, 0, 0);
        }
    };

    GKV(0, kA0, kA1, vA0, vA1);
    #pragma unroll 1
    for (int kt = 0; kt < 16; kt += 2) {
        WKV(0, kA0, kA1, vA0, vA1);
        __syncthreads();
        GKV(kt + 1, kB0, kB1, vB0, vB1);
        compute(0);
        WKV(1, kB0, kB1, vB0, vB1);
        __syncthreads();
        if (kt + 2 < 16) GKV(kt + 2, kA0, kA1, vA0, vA1);
        compute(1);
    }
#undef GKV
#undef WKV

    float il0 = 1.f / __shfl(lrun, quad * 4 + 0);
    float il1 = 1.f / __shfl(lrun, quad * 4 + 1);
    float il2 = 1.f / __shfl(lrun, quad * 4 + 2);
    float il3 = 1.f / __shfl(lrun, quad * 4 + 3);
    __hip_bfloat16* orow =
        o_out + (long)(b * 1024 + qt * 64 + wave * 16) * CDIM + hh * DHEAD;
    #pragma unroll
    for (int db = 0; db < 4; ++db) {
        int col = db * 16 + l;
        orow[(quad * 4 + 0) * CDIM + col] = __float2bfloat16(facc[db][0] * il0);
        orow[(quad * 4 + 1) * CDIM + col] = __float2bfloat16(facc[db][1] * il1);
        orow[(quad * 4 + 2) * CDIM + col] = __float2bfloat16(facc[db][2] * il2);
        orow[(quad * 4 + 3) * CDIM + col] = __float2bfloat16(facc[db][3] * il3);
    }
}

// ---------------------------------------------------------------------------
extern "C" void kernel_launch(void* const* d_in, const int* in_sizes, int n_in,
                              void* d_out, int out_size, void* d_ws, size_t ws_size,
                              hipStream_t stream)
{
    const float* x      = (const float*)d_in[0];
    const float* qkv_w  = (const float*)d_in[1];
    const float* proj_w = (const float*)d_in[2];
    const float* proj_b = (const float*)d_in[3];
    const float* fc1_w  = (const float*)d_in[4];
    const float* fc1_b  = (const float*)d_in[5];
    const float* fc2_w  = (const float*)d_in[6];
    const float* fc2_b  = (const float*)d_in[7];
    const float* ln1_g  = (const float*)d_in[8];
    const float* ln1_b  = (const float*)d_in[9];
    const float* ln2_g  = (const float*)d_in[10];
    const float* ln2_b  = (const float*)d_in[11];
    const float* lnh_g  = (const float*)d_in[12];
    const float* lnh_b  = (const float*)d_in[13];

    float* out = (float*)d_out;

    __hip_bfloat16* wsb     = (__hip_bfloat16*)d_ws;
    __hip_bfloat16* qkvw_bf = wsb;
    __hip_bfloat16* fc1w_bf = qkvw_bf + 3l * 1024 * 1024;
    __hip_bfloat16* fc2w_bf = fc1w_bf + 4l * 1024 * 1024;
    __hip_bfloat16* projw_bf= fc2w_bf + 4l * 1024 * 1024;
    __hip_bfloat16* h_bf    = projw_bf + 1l * 1024 * 1024;
    __hip_bfloat16* qkv_bf  = h_bf + 4l * 1024 * 1024;
    __hip_bfloat16* o_bf    = qkv_bf + 12l * 1024 * 1024;
    __hip_bfloat16* u_bf    = o_bf + 4l * 1024 * 1024;

    // 0. all weights fp32 -> bf16
    cvt_all<<<12288, 256, 0, stream>>>(qkv_w, fc1_w, fc2_w, proj_w, qkvw_bf);

    // 1. h = LN1(x)
    ln_f32_kernel<<<TOKENS, 256, 0, stream>>>(x, ln1_g, ln1_b, h_bf, CDIM);
    // 2. qkv = h @ qkv_w^T
    gemm_mfma<128><<<dim3(3072 / 128, TOKENS / 128), 256, 0, stream>>>(
        h_bf, qkvw_bf, nullptr, nullptr, qkv_bf, TOKENS, 3072, CDIM, 0, 1);
    // 3. o = attention(qkv)
    attn_mfma<<<1024, 256, 0, stream>>>(qkv_bf, o_bf);
    // 4. out = x + o @ proj_w^T + proj_b
    gemm_mfma<64><<<dim3(CDIM / 64, TOKENS / 128), 256, 0, stream>>>(
        o_bf, projw_bf, proj_b, x, out, TOKENS, CDIM, CDIM, 0, 0);
    // 5. h2 = LN2(out)
    ln_f32_kernel<<<TOKENS, 256, 0, stream>>>(out, ln2_g, ln2_b, h_bf, CDIM);
    // 6. u = gelu(h2 @ fc1_w^T + fc1_b)
    gemm_mfma<128><<<dim3(HID / 128, TOKENS / 128), 256, 0, stream>>>(
        h_bf, fc1w_bf, fc1_b, nullptr, u_bf, TOKENS, HID, CDIM, 1, 1);
    // 7. u = LNh(u) in place
    ln_bf16_kernel<<<TOKENS, 256, 0, stream>>>(u_bf, lnh_g, lnh_b, u_bf, HID);
    // 8. out = out + u @ fc2_w^T + fc2_b
    gemm_mfma<64><<<dim3(CDIM / 64, TOKENS / 128), 256, 0, stream>>>(
        u_bf, fc2w_bf, fc2_b, out, out, TOKENS, CDIM, HID, 0, 0);
}

// Round 8
// 376.661 us; speedup vs baseline: 2.1240x; 2.1240x over previous
//
#include <hip/hip_runtime.h>
#include <hip/hip_bf16.h>
#include <math.h>

// ---------------------------------------------------------------------------
// Transformer block. R7 (rebuilt from R4-best + targeted changes):
//  - gemm128 (qkv, fc1): R4 reg-staged distance-1 pipeline (straight-line
//    named uint4 regs - NO arrays/lambdas: R6's arrays got demoted to scratch,
//    WRITE_SIZE 157-403 MB, 2x regression) + XCD-compact swizzle (R5: FETCH
//    143->41 MB).
//  - gemm64 (proj, fc2): NEW 64x64 tile kernel -> 1024 blocks = 4/CU
//    (was 512 = 2/CU), 2 uint4/thread staging, acc 16 VGPRs.
//  - LN kernels vectorized (R6). GELU sigmoid form (R6, passed).
//  - Attention: R5 pipelined MFMA flash kernel (unchanged).
// ---------------------------------------------------------------------------

#define TOKENS 4096
#define CDIM   1024
#define HEADS  16
#define DHEAD  64
#define HID    4096

typedef __attribute__((ext_vector_type(4))) float  floatx4;
typedef __attribute__((ext_vector_type(8))) short  short8;  // 8 x bf16 frag

// ---------------- fused fp32 -> bf16 weight convert ----------------
__global__ __launch_bounds__(256) void cvt_all(
    const float* __restrict__ s0, const float* __restrict__ s1,
    const float* __restrict__ s2, const float* __restrict__ s3,
    __hip_bfloat16* __restrict__ dst)
{
    long i = (long)blockIdx.x * 256 + threadIdx.x;   // float4 index, 3M total
    const float* src;
    long base;
    if (i < 768l * 1024)       { src = s0; base = 0; }
    else if (i < 1792l * 1024) { src = s1; base = 768l * 1024; }
    else if (i < 2816l * 1024) { src = s2; base = 1792l * 1024; }
    else                       { src = s3; base = 2816l * 1024; }
    float4 v = ((const float4*)src)[i - base];
    __hip_bfloat16 t[4];
    t[0] = __float2bfloat16(v.x);
    t[1] = __float2bfloat16(v.y);
    t[2] = __float2bfloat16(v.z);
    t[3] = __float2bfloat16(v.w);
    *(uint2*)(dst + 4l * i) = *(uint2*)t;
}

// ---------------- LayerNorm: fp32 in -> bf16 out (vectorized) --------------
__global__ __launch_bounds__(256) void ln_f32_kernel(
    const float* __restrict__ x, const float* __restrict__ g,
    const float* __restrict__ b, __hip_bfloat16* __restrict__ y, int C)
{
    int row = blockIdx.x;
    const float4* xr = (const float4*)(x + (long)row * C);
    uint2* yr = (uint2*)(y + (long)row * C);
    const int C4 = C >> 2;

    float s = 0.f, ss = 0.f;
    for (int i = threadIdx.x; i < C4; i += 256) {
        float4 v = xr[i];
        s  += v.x + v.y + v.z + v.w;
        ss += v.x * v.x + v.y * v.y + v.z * v.z + v.w * v.w;
    }
    #pragma unroll
    for (int d = 32; d; d >>= 1) {
        s  += __shfl_down(s, d);
        ss += __shfl_down(ss, d);
    }
    __shared__ float buf[4][2];
    int wid = threadIdx.x >> 6, lane = threadIdx.x & 63;
    if (lane == 0) { buf[wid][0] = s; buf[wid][1] = ss; }
    __syncthreads();
    if (threadIdx.x == 0) {
        s = buf[0][0] + buf[1][0] + buf[2][0] + buf[3][0];
        ss = buf[0][1] + buf[1][1] + buf[2][1] + buf[3][1];
        buf[0][0] = s; buf[0][1] = ss;
    }
    __syncthreads();
    s = buf[0][0]; ss = buf[0][1];

    float invC = 1.f / (float)C;
    float mu = s * invC;
    float var = ss * invC - mu * mu;
    float inv = rsqrtf(var + 1e-5f);
    const float4* gg = (const float4*)g;
    const float4* bb = (const float4*)b;
    for (int i = threadIdx.x; i < C4; i += 256) {
        float4 v = xr[i], gv = gg[i], bv = bb[i];
        __hip_bfloat16 t[4];
        t[0] = __float2bfloat16((v.x - mu) * inv * gv.x + bv.x);
        t[1] = __float2bfloat16((v.y - mu) * inv * gv.y + bv.y);
        t[2] = __float2bfloat16((v.z - mu) * inv * gv.z + bv.z);
        t[3] = __float2bfloat16((v.w - mu) * inv * gv.w + bv.w);
        yr[i] = *(uint2*)t;
    }
}

// ---------------- LayerNorm: bf16 in -> bf16 out (vectorized, in place ok) --
__global__ __launch_bounds__(256) void ln_bf16_kernel(
    const __hip_bfloat16* __restrict__ x, const float* __restrict__ g,
    const float* __restrict__ b, __hip_bfloat16* __restrict__ y, int C)
{
    int row = blockIdx.x;
    const uint4* xr = (const uint4*)(x + (long)row * C);
    uint4* yr = (uint4*)(y + (long)row * C);
    const int C8 = C >> 3;

    float s = 0.f, ss = 0.f;
    for (int i = threadIdx.x; i < C8; i += 256) {
        uint4 raw = xr[i];
        const __hip_bfloat16* p = (const __hip_bfloat16*)&raw;
        #pragma unroll
        for (int j = 0; j < 8; ++j) {
            float v = __bfloat162float(p[j]);
            s += v; ss += v * v;
        }
    }
    #pragma unroll
    for (int d = 32; d; d >>= 1) {
        s  += __shfl_down(s, d);
        ss += __shfl_down(ss, d);
    }
    __shared__ float buf[4][2];
    int wid = threadIdx.x >> 6, lane = threadIdx.x & 63;
    if (lane == 0) { buf[wid][0] = s; buf[wid][1] = ss; }
    __syncthreads();
    if (threadIdx.x == 0) {
        s = buf[0][0] + buf[1][0] + buf[2][0] + buf[3][0];
        ss = buf[0][1] + buf[1][1] + buf[2][1] + buf[3][1];
        buf[0][0] = s; buf[0][1] = ss;
    }
    __syncthreads();
    s = buf[0][0]; ss = buf[0][1];

    float invC = 1.f / (float)C;
    float mu = s * invC;
    float var = ss * invC - mu * mu;
    float inv = rsqrtf(var + 1e-5f);
    const float4* gg = (const float4*)g;
    const float4* bb = (const float4*)b;
    for (int i = threadIdx.x; i < C8; i += 256) {
        uint4 raw = xr[i];
        const __hip_bfloat16* p = (const __hip_bfloat16*)&raw;
        float4 g0 = gg[2 * i], g1 = gg[2 * i + 1];
        float4 b0 = bb[2 * i], b1 = bb[2 * i + 1];
        __hip_bfloat16 t[8];
        t[0] = __float2bfloat16((__bfloat162float(p[0]) - mu) * inv * g0.x + b0.x);
        t[1] = __float2bfloat16((__bfloat162float(p[1]) - mu) * inv * g0.y + b0.y);
        t[2] = __float2bfloat16((__bfloat162float(p[2]) - mu) * inv * g0.z + b0.z);
        t[3] = __float2bfloat16((__bfloat162float(p[3]) - mu) * inv * g0.w + b0.w);
        t[4] = __float2bfloat16((__bfloat162float(p[4]) - mu) * inv * g1.x + b1.x);
        t[5] = __float2bfloat16((__bfloat162float(p[5]) - mu) * inv * g1.y + b1.y);
        t[6] = __float2bfloat16((__bfloat162float(p[6]) - mu) * inv * g1.z + b1.z);
        t[7] = __float2bfloat16((__bfloat162float(p[7]) - mu) * inv * g1.w + b1.w);
        yr[i] = *(uint4*)t;
    }
}

// ---------------- gemm128: 128x128 tile, bf16 out, optional bias/gelu ------
// C = A[M,K] @ W[N,K]^T. 256 threads = 4 waves 2x2, wave tile 64x64.
// R4 reg-staged distance-1 pipeline, straight-line named regs, + XCD swizzle.
__global__ __launch_bounds__(256, 3) void gemm128(
    const __hip_bfloat16* __restrict__ A,
    const __hip_bfloat16* __restrict__ W,
    const float* __restrict__ bias,
    __hip_bfloat16* __restrict__ Cout, int M, int N, int K, int act)
{
    __shared__ __hip_bfloat16 Asl[2][128 * 32];
    __shared__ __hip_bfloat16 Bsl[2][128 * 32];

    int tid = threadIdx.x;
    int wave = tid >> 6, lane = tid & 63;

    // XCD-compact swizzle: XCD = lin % 8 owns a contiguous M-tile band.
    int mt, nt;
    {
        int gx = gridDim.x, gy = gridDim.y;
        int lin = blockIdx.y * gx + blockIdx.x;
        int chunk = gy >> 3;                // gy is 32 here
        int xcd = lin & 7, q = lin >> 3;
        mt = xcd * chunk + (q % chunk);
        nt = q / chunk;
    }
    int bm = mt * 128, bn = nt * 128;
    int wm = wave & 1, wn = wave >> 1;
    int fm = lane & 15, quad = lane >> 4;

    int srow = lane >> 2;          // 0..15
    int skk  = (lane & 3) * 8;     // 0,8,16,24

    const __hip_bfloat16* Ap = A + (long)(bm + wave * 16 + srow) * K + skk;
    const __hip_bfloat16* Bp = W + (long)(bn + wave * 16 + srow) * K + skk;
    const long a64 = (long)64 * K;

    const int nk = K / 32;
    floatx4 acc[4][4] = {};
    const int aoff = (wave * 16 + srow) * 32 + skk;

    // tile 0 -> regs -> buf 0
    uint4 a0 = *(const uint4*)(Ap);
    uint4 a1 = *(const uint4*)(Ap + a64);
    uint4 b0 = *(const uint4*)(Bp);
    uint4 b1 = *(const uint4*)(Bp + a64);

    *(uint4*)&Asl[0][aoff] = a0;
    *(uint4*)&Asl[0][aoff + 2048] = a1;
    *(uint4*)&Bsl[0][aoff] = b0;
    *(uint4*)&Bsl[0][aoff + 2048] = b1;

    // tile 1 -> regs
    a0 = *(const uint4*)(Ap + 32);
    a1 = *(const uint4*)(Ap + a64 + 32);
    b0 = *(const uint4*)(Bp + 32);
    b1 = *(const uint4*)(Bp + a64 + 32);

    __syncthreads();

    for (int kt = 0; kt < nk; ++kt) {
        const int buf = kt & 1;
        const __hip_bfloat16* Ab = Asl[buf];
        const __hip_bfloat16* Bb = Bsl[buf];

        short8 bfr[4];
        #pragma unroll
        for (int j = 0; j < 4; ++j)
            bfr[j] = *(const short8*)(Bb + (wn * 64 + j * 16 + fm) * 32 + quad * 8);
        #pragma unroll
        for (int i = 0; i < 4; ++i) {
            short8 af = *(const short8*)(Ab + (wm * 64 + i * 16 + fm) * 32 + quad * 8);
            #pragma unroll
            for (int j = 0; j < 4; ++j)
                acc[i][j] = __builtin_amdgcn_mfma_f32_16x16x32_bf16(
                    af, bfr[j], acc[i][j], 0, 0, 0);
        }

        if (kt + 1 < nk) {
            const int nb = buf ^ 1;
            *(uint4*)&Asl[nb][aoff] = a0;            // vmcnt wait lands here,
            *(uint4*)&Asl[nb][aoff + 2048] = a1;     // one iter after issue
            *(uint4*)&Bsl[nb][aoff] = b0;
            *(uint4*)&Bsl[nb][aoff + 2048] = b1;
            if (kt + 2 < nk) {
                const long o = (long)(kt + 2) * 32;
                a0 = *(const uint4*)(Ap + o);
                a1 = *(const uint4*)(Ap + a64 + o);
                b0 = *(const uint4*)(Bp + o);
                b1 = *(const uint4*)(Bp + a64 + o);
            }
        }
        __syncthreads();   // lgkm drain only (ds_writes) — no vmcnt(0)
    }

    int mbase = bm + wm * 64;
    int nbase = bn + wn * 64;
    #pragma unroll
    for (int i = 0; i < 4; ++i) {
        #pragma unroll
        for (int j = 0; j < 4; ++j) {
            int ncol = nbase + j * 16 + fm;
            #pragma unroll
            for (int r = 0; r < 4; ++r) {
                int mrow = mbase + i * 16 + quad * 4 + r;
                float v = acc[i][j][r];
                if (bias) v += bias[ncol];
                if (act == 1) {
                    float z = v * (1.5957691216f + 0.0713548162f * v * v);
                    v = v / (1.f + __expf(-z));
                }
                Cout[(long)mrow * N + ncol] = __float2bfloat16(v);
            }
        }
    }
}

// ---------------- gemm64: 64x64 tile, f32 out, bias+residual always --------
// C = A[M,K] @ W[N,K]^T + bias + residual. 256 threads = 4 waves 2x2,
// wave tile 32x32. 1024 blocks -> 4/CU. Staging: 1 A + 1 B uint4 per thread.
__global__ __launch_bounds__(256, 4) void gemm64(
    const __hip_bfloat16* __restrict__ A,
    const __hip_bfloat16* __restrict__ W,
    const float* __restrict__ bias, const float* __restrict__ residual,
    float* __restrict__ Cout, int M, int N, int K)
{
    __shared__ __hip_bfloat16 Asl[2][64 * 32];
    __shared__ __hip_bfloat16 Bsl[2][64 * 32];

    int tid = threadIdx.x;
    int wave = tid >> 6, lane = tid & 63;

    int mt, nt;
    {
        int gx = gridDim.x, gy = gridDim.y;
        int lin = blockIdx.y * gx + blockIdx.x;
        int chunk = gy >> 3;                // gy is 64 here
        int xcd = lin & 7, q = lin >> 3;
        mt = xcd * chunk + (q % chunk);
        nt = q / chunk;
    }
    int bm = mt * 64, bn = nt * 64;
    int wm = wave & 1, wn = wave >> 1;
    int fm = lane & 15, quad = lane >> 4;

    int srow = tid >> 2;           // 0..63
    int skk  = (tid & 3) * 8;      // 0,8,16,24

    const __hip_bfloat16* Ap = A + (long)(bm + srow) * K + skk;
    const __hip_bfloat16* Bp = W + (long)(bn + srow) * K + skk;

    const int nk = K / 32;
    floatx4 acc[2][2] = {};
    const int aoff = srow * 32 + skk;

    uint4 a0 = *(const uint4*)(Ap);
    uint4 b0 = *(const uint4*)(Bp);
    *(uint4*)&Asl[0][aoff] = a0;
    *(uint4*)&Bsl[0][aoff] = b0;
    a0 = *(const uint4*)(Ap + 32);
    b0 = *(const uint4*)(Bp + 32);

    __syncthreads();

    for (int kt = 0; kt < nk; ++kt) {
        const int buf = kt & 1;
        const __hip_bfloat16* Ab = Asl[buf];
        const __hip_bfloat16* Bb = Bsl[buf];

        short8 bf0 = *(const short8*)(Bb + (wn * 32 + fm) * 32 + quad * 8);
        short8 bf1 = *(const short8*)(Bb + (wn * 32 + 16 + fm) * 32 + quad * 8);
        short8 af0 = *(const short8*)(Ab + (wm * 32 + fm) * 32 + quad * 8);
        short8 af1 = *(const short8*)(Ab + (wm * 32 + 16 + fm) * 32 + quad * 8);
        acc[0][0] = __builtin_amdgcn_mfma_f32_16x16x32_bf16(af0, bf0, acc[0][0], 0, 0, 0);
        acc[0][1] = __builtin_amdgcn_mfma_f32_16x16x32_bf16(af0, bf1, acc[0][1], 0, 0, 0);
        acc[1][0] = __builtin_amdgcn_mfma_f32_16x16x32_bf16(af1, bf0, acc[1][0], 0, 0, 0);
        acc[1][1] = __builtin_amdgcn_mfma_f32_16x16x32_bf16(af1, bf1, acc[1][1], 0, 0, 0);

        if (kt + 1 < nk) {
            const int nb = buf ^ 1;
            *(uint4*)&Asl[nb][aoff] = a0;
            *(uint4*)&Bsl[nb][aoff] = b0;
            if (kt + 2 < nk) {
                const long o = (long)(kt + 2) * 32;
                a0 = *(const uint4*)(Ap + o);
                b0 = *(const uint4*)(Bp + o);
            }
        }
        __syncthreads();
    }

    int mbase = bm + wm * 32;
    int nbase = bn + wn * 32;
    #pragma unroll
    for (int i = 0; i < 2; ++i) {
        #pragma unroll
        for (int j = 0; j < 2; ++j) {
            int ncol = nbase + j * 16 + fm;
            #pragma unroll
            for (int r = 0; r < 4; ++r) {
                int mrow = mbase + i * 16 + quad * 4 + r;
                float v = acc[i][j][r] + bias[ncol]
                        + residual[(long)mrow * N + ncol];
                Cout[(long)mrow * N + ncol] = v;
            }
        }
    }
}

// ---------------- MFMA flash attention, pipelined (R5, unchanged) ----------
__global__ __launch_bounds__(256) void attn_mfma(
    const __hip_bfloat16* __restrict__ qkv, __hip_bfloat16* __restrict__ o_out)
{
    __shared__ __align__(16) char Ks[2][64 * 144];
    __shared__ __align__(16) char Vt[2][64 * 144];
    __shared__ __align__(16) char Ps[4 * 16 * 144];

    const int C3 = 3 * CDIM;
    int lin = blockIdx.x;
    int xcd = lin & 7, q = lin >> 3;
    int bh = xcd * 8 + (q >> 4);
    int qt = q & 15;
    int b = bh >> 4, hh = bh & 15;
    int tid = threadIdx.x, wave = tid >> 6, lane = tid & 63;
    int l = lane & 15, quad = lane >> 4;

    const __hip_bfloat16* qrow =
        qkv + (long)(b * 1024 + qt * 64 + wave * 16 + l) * C3 + hh * DHEAD;
    short8 qf0 = *(const short8*)(qrow + quad * 8);
    short8 qf1 = *(const short8*)(qrow + 32 + quad * 8);

    char* Psw = Ps + wave * (16 * 144);

    int sc = tid & 7;
    int skl = tid >> 3;

    const __hip_bfloat16* Kbase = qkv + (long)(b * 1024) * C3 + CDIM + hh * DHEAD;
    const __hip_bfloat16* Vbase = qkv + (long)(b * 1024) * C3 + 2 * CDIM + hh * DHEAD;
    const int kpp = skl ^ (sc << 2);

    floatx4 facc[4] = {};
    float mrun = -1e30f, lrun = 0.f;

    uint4 kA0, kA1, vA0, vA1;
    uint4 kB0, kB1, vB0, vB1;

#define GKV(t, k0, k1, v0, v1) { \
    const __hip_bfloat16* Kg = Kbase + (long)((t) * 64) * C3; \
    const __hip_bfloat16* Vg = Vbase + (long)((t) * 64) * C3; \
    k0 = *(const uint4*)(Kg + (long)skl * C3 + sc * 8); \
    k1 = *(const uint4*)(Kg + (long)(skl + 32) * C3 + sc * 8); \
    v0 = *(const uint4*)(Vg + (long)(2 * skl) * C3 + sc * 8); \
    v1 = *(const uint4*)(Vg + (long)(2 * skl + 1) * C3 + sc * 8); }
#define WKV(bf, k0, k1, v0, v1) { \
    *(uint4*)(Ks[bf] + skl * 144 + sc * 16) = k0; \
    *(uint4*)(Ks[bf] + (skl + 32) * 144 + sc * 16) = k1; \
    const ushort* e0 = (const ushort*)&v0; \
    const ushort* e1 = (const ushort*)&v1; \
    _Pragma("unroll") \
    for (int j = 0; j < 8; ++j) { \
        unsigned dw = (unsigned)e0[j] | ((unsigned)e1[j] << 16); \
        *(unsigned*)(Vt[bf] + (sc * 8 + j) * 144 + kpp * 4) = dw; \
    } }

    auto compute = [&](int buf) {
        floatx4 st[4] = {};
        #pragma unroll
        for (int kb = 0; kb < 4; ++kb) {
            short8 k0 = *(const short8*)(Ks[buf] + (kb * 16 + l) * 144 + quad * 16);
            short8 k1 = *(const short8*)(Ks[buf] + (kb * 16 + l) * 144 + 64 + quad * 16);
            st[kb] = __builtin_amdgcn_mfma_f32_16x16x32_bf16(k0, qf0, st[kb], 0, 0, 0);
            st[kb] = __builtin_amdgcn_mfma_f32_16x16x32_bf16(k1, qf1, st[kb], 0, 0, 0);
        }
        float p[16];
        float tm = -1e30f;
        #pragma unroll
        for (int kb = 0; kb < 4; ++kb)
            #pragma unroll
            for (int r = 0; r < 4; ++r) {
                float s = st[kb][r] * 0.125f;
                p[kb * 4 + r] = s;
                tm = fmaxf(tm, s);
            }
        tm = fmaxf(tm, __shfl_xor(tm, 16));
        tm = fmaxf(tm, __shfl_xor(tm, 32));
        float mn = fmaxf(mrun, tm);
        float alpha = __expf(mrun - mn);
        float psum = 0.f;
        #pragma unroll
        for (int i = 0; i < 16; ++i) { p[i] = __expf(p[i] - mn); psum += p[i]; }
        psum += __shfl_xor(psum, 16);
        psum += __shfl_xor(psum, 32);
        lrun = lrun * alpha + psum;
        mrun = mn;

        #pragma unroll
        for (int kb = 0; kb < 4; ++kb) {
            __hip_bfloat16 t[4];
            #pragma unroll
            for (int r = 0; r < 4; ++r) t[r] = __float2bfloat16(p[kb * 4 + r]);
            *(uint2*)(Psw + l * 144 + kb * 32 + quad * 8) = *(const uint2*)t;
        }

        float a0 = __shfl(alpha, quad * 4 + 0);
        float a1 = __shfl(alpha, quad * 4 + 1);
        float a2 = __shfl(alpha, quad * 4 + 2);
        float a3 = __shfl(alpha, quad * 4 + 3);
        #pragma unroll
        for (int db = 0; db < 4; ++db) {
            facc[db][0] *= a0; facc[db][1] *= a1;
            facc[db][2] *= a2; facc[db][3] *= a3;
        }

        short8 pf0 = *(const short8*)(Psw + l * 144 + quad * 16);
        short8 pf1 = *(const short8*)(Psw + l * 144 + 64 + quad * 16);
        #pragma unroll
        for (int db = 0; db < 4; ++db) {
            int d = db * 16 + l;
            int o3 = (d >> 3) & 7;
            short8 v0 = *(const short8*)(Vt[buf] + d * 144 + ((quad ^ o3) << 4));
            short8 v1 = *(const short8*)(Vt[buf] + d * 144 + (((4 + quad) ^ o3) << 4));
            facc[db] = __builtin_amdgcn_mfma_f32_16x16x32_bf16(pf0, v0, facc[db], 0, 0, 0);
            facc[db] = __builtin_amdgcn_mfma_f32_16x16x32_bf16(pf1, v1, facc[db], 0, 0, 0);
        }
    };

    GKV(0, kA0, kA1, vA0, vA1);
    #pragma unroll 1
    for (int kt = 0; kt < 16; kt += 2) {
        WKV(0, kA0, kA1, vA0, vA1);
        __syncthreads();
        GKV(kt + 1, kB0, kB1, vB0, vB1);
        compute(0);
        WKV(1, kB0, kB1, vB0, vB1);
        __syncthreads();
        if (kt + 2 < 16) GKV(kt + 2, kA0, kA1, vA0, vA1);
        compute(1);
    }
#undef GKV
#undef WKV

    float il0 = 1.f / __shfl(lrun, quad * 4 + 0);
    float il1 = 1.f / __shfl(lrun, quad * 4 + 1);
    float il2 = 1.f / __shfl(lrun, quad * 4 + 2);
    float il3 = 1.f / __shfl(lrun, quad * 4 + 3);
    __hip_bfloat16* orow =
        o_out + (long)(b * 1024 + qt * 64 + wave * 16) * CDIM + hh * DHEAD;
    #pragma unroll
    for (int db = 0; db < 4; ++db) {
        int col = db * 16 + l;
        orow[(quad * 4 + 0) * CDIM + col] = __float2bfloat16(facc[db][0] * il0);
        orow[(quad * 4 + 1) * CDIM + col] = __float2bfloat16(facc[db][1] * il1);
        orow[(quad * 4 + 2) * CDIM + col] = __float2bfloat16(facc[db][2] * il2);
        orow[(quad * 4 + 3) * CDIM + col] = __float2bfloat16(facc[db][3] * il3);
    }
}

// ---------------------------------------------------------------------------
extern "C" void kernel_launch(void* const* d_in, const int* in_sizes, int n_in,
                              void* d_out, int out_size, void* d_ws, size_t ws_size,
                              hipStream_t stream)
{
    const float* x      = (const float*)d_in[0];
    const float* qkv_w  = (const float*)d_in[1];
    const float* proj_w = (const float*)d_in[2];
    const float* proj_b = (const float*)d_in[3];
    const float* fc1_w  = (const float*)d_in[4];
    const float* fc1_b  = (const float*)d_in[5];
    const float* fc2_w  = (const float*)d_in[6];
    const float* fc2_b  = (const float*)d_in[7];
    const float* ln1_g  = (const float*)d_in[8];
    const float* ln1_b  = (const float*)d_in[9];
    const float* ln2_g  = (const float*)d_in[10];
    const float* ln2_b  = (const float*)d_in[11];
    const float* lnh_g  = (const float*)d_in[12];
    const float* lnh_b  = (const float*)d_in[13];

    float* out = (float*)d_out;

    __hip_bfloat16* wsb     = (__hip_bfloat16*)d_ws;
    __hip_bfloat16* qkvw_bf = wsb;
    __hip_bfloat16* fc1w_bf = qkvw_bf + 3l * 1024 * 1024;
    __hip_bfloat16* fc2w_bf = fc1w_bf + 4l * 1024 * 1024;
    __hip_bfloat16* projw_bf= fc2w_bf + 4l * 1024 * 1024;
    __hip_bfloat16* h_bf    = projw_bf + 1l * 1024 * 1024;
    __hip_bfloat16* qkv_bf  = h_bf + 4l * 1024 * 1024;
    __hip_bfloat16* o_bf    = qkv_bf + 12l * 1024 * 1024;
    __hip_bfloat16* u_bf    = o_bf + 4l * 1024 * 1024;

    // 0. all weights fp32 -> bf16
    cvt_all<<<12288, 256, 0, stream>>>(qkv_w, fc1_w, fc2_w, proj_w, qkvw_bf);

    // 1. h = LN1(x)
    ln_f32_kernel<<<TOKENS, 256, 0, stream>>>(x, ln1_g, ln1_b, h_bf, CDIM);
    // 2. qkv = h @ qkv_w^T
    gemm128<<<dim3(3072 / 128, TOKENS / 128), 256, 0, stream>>>(
        h_bf, qkvw_bf, nullptr, qkv_bf, TOKENS, 3072, CDIM, 0);
    // 3. o = attention(qkv)
    attn_mfma<<<1024, 256, 0, stream>>>(qkv_bf, o_bf);
    // 4. out = x + o @ proj_w^T + proj_b
    gemm64<<<dim3(CDIM / 64, TOKENS / 64), 256, 0, stream>>>(
        o_bf, projw_bf, proj_b, x, out, TOKENS, CDIM, CDIM);
    // 5. h2 = LN2(out)
    ln_f32_kernel<<<TOKENS, 256, 0, stream>>>(out, ln2_g, ln2_b, h_bf, CDIM);
    // 6. u = gelu(h2 @ fc1_w^T + fc1_b)
    gemm128<<<dim3(HID / 128, TOKENS / 128), 256, 0, stream>>>(
        h_bf, fc1w_bf, fc1_b, u_bf, TOKENS, HID, CDIM, 1);
    // 7. u = LNh(u) in place
    ln_bf16_kernel<<<TOKENS, 256, 0, stream>>>(u_bf, lnh_g, lnh_b, u_bf, HID);
    // 8. out = out + u @ fc2_w^T + fc2_b
    gemm64<<<dim3(CDIM / 64, TOKENS / 64), 256, 0, stream>>>(
        u_bf, fc2w_bf, fc2_b, out, out, TOKENS, CDIM, HID);
}

// Round 9
// 366.592 us; speedup vs baseline: 2.1823x; 1.0275x over previous
//
#include <hip/hip_runtime.h>
#include <hip/hip_bf16.h>
#include <math.h>

// ---------------------------------------------------------------------------
// Transformer block. R8:
//  - gemm64 (proj, fc2): BK=64 double-buffer (half the barriers of R7),
//    named-reg staging (4 uint4), LDS row stride 144 B (bank group (9r+c)%8,
//    odd multiplier -> conflict spread). 36.9 kB LDS, 4 blocks/CU.
//  - gemm128 (qkv, fc1): R7 pipeline, LDS row stride 64 -> 80 B (bank group
//    (5r+q)%8) to kill the measured 4.2M-conflict counter.
//  - LN vectorized, GELU sigmoid form, attention R5 (all unchanged).
// ---------------------------------------------------------------------------

#define TOKENS 4096
#define CDIM   1024
#define HEADS  16
#define DHEAD  64
#define HID    4096

typedef __attribute__((ext_vector_type(4))) float  floatx4;
typedef __attribute__((ext_vector_type(8))) short  short8;  // 8 x bf16 frag

// ---------------- fused fp32 -> bf16 weight convert ----------------
__global__ __launch_bounds__(256) void cvt_all(
    const float* __restrict__ s0, const float* __restrict__ s1,
    const float* __restrict__ s2, const float* __restrict__ s3,
    __hip_bfloat16* __restrict__ dst)
{
    long i = (long)blockIdx.x * 256 + threadIdx.x;   // float4 index, 3M total
    const float* src;
    long base;
    if (i < 768l * 1024)       { src = s0; base = 0; }
    else if (i < 1792l * 1024) { src = s1; base = 768l * 1024; }
    else if (i < 2816l * 1024) { src = s2; base = 1792l * 1024; }
    else                       { src = s3; base = 2816l * 1024; }
    float4 v = ((const float4*)src)[i - base];
    __hip_bfloat16 t[4];
    t[0] = __float2bfloat16(v.x);
    t[1] = __float2bfloat16(v.y);
    t[2] = __float2bfloat16(v.z);
    t[3] = __float2bfloat16(v.w);
    *(uint2*)(dst + 4l * i) = *(uint2*)t;
}

// ---------------- LayerNorm: fp32 in -> bf16 out (vectorized) --------------
__global__ __launch_bounds__(256) void ln_f32_kernel(
    const float* __restrict__ x, const float* __restrict__ g,
    const float* __restrict__ b, __hip_bfloat16* __restrict__ y, int C)
{
    int row = blockIdx.x;
    const float4* xr = (const float4*)(x + (long)row * C);
    uint2* yr = (uint2*)(y + (long)row * C);
    const int C4 = C >> 2;

    float s = 0.f, ss = 0.f;
    for (int i = threadIdx.x; i < C4; i += 256) {
        float4 v = xr[i];
        s  += v.x + v.y + v.z + v.w;
        ss += v.x * v.x + v.y * v.y + v.z * v.z + v.w * v.w;
    }
    #pragma unroll
    for (int d = 32; d; d >>= 1) {
        s  += __shfl_down(s, d);
        ss += __shfl_down(ss, d);
    }
    __shared__ float buf[4][2];
    int wid = threadIdx.x >> 6, lane = threadIdx.x & 63;
    if (lane == 0) { buf[wid][0] = s; buf[wid][1] = ss; }
    __syncthreads();
    if (threadIdx.x == 0) {
        s = buf[0][0] + buf[1][0] + buf[2][0] + buf[3][0];
        ss = buf[0][1] + buf[1][1] + buf[2][1] + buf[3][1];
        buf[0][0] = s; buf[0][1] = ss;
    }
    __syncthreads();
    s = buf[0][0]; ss = buf[0][1];

    float invC = 1.f / (float)C;
    float mu = s * invC;
    float var = ss * invC - mu * mu;
    float inv = rsqrtf(var + 1e-5f);
    const float4* gg = (const float4*)g;
    const float4* bb = (const float4*)b;
    for (int i = threadIdx.x; i < C4; i += 256) {
        float4 v = xr[i], gv = gg[i], bv = bb[i];
        __hip_bfloat16 t[4];
        t[0] = __float2bfloat16((v.x - mu) * inv * gv.x + bv.x);
        t[1] = __float2bfloat16((v.y - mu) * inv * gv.y + bv.y);
        t[2] = __float2bfloat16((v.z - mu) * inv * gv.z + bv.z);
        t[3] = __float2bfloat16((v.w - mu) * inv * gv.w + bv.w);
        yr[i] = *(uint2*)t;
    }
}

// ---------------- LayerNorm: bf16 in -> bf16 out (vectorized, in place ok) --
__global__ __launch_bounds__(256) void ln_bf16_kernel(
    const __hip_bfloat16* __restrict__ x, const float* __restrict__ g,
    const float* __restrict__ b, __hip_bfloat16* __restrict__ y, int C)
{
    int row = blockIdx.x;
    const uint4* xr = (const uint4*)(x + (long)row * C);
    uint4* yr = (uint4*)(y + (long)row * C);
    const int C8 = C >> 3;

    float s = 0.f, ss = 0.f;
    for (int i = threadIdx.x; i < C8; i += 256) {
        uint4 raw = xr[i];
        const __hip_bfloat16* p = (const __hip_bfloat16*)&raw;
        #pragma unroll
        for (int j = 0; j < 8; ++j) {
            float v = __bfloat162float(p[j]);
            s += v; ss += v * v;
        }
    }
    #pragma unroll
    for (int d = 32; d; d >>= 1) {
        s  += __shfl_down(s, d);
        ss += __shfl_down(ss, d);
    }
    __shared__ float buf[4][2];
    int wid = threadIdx.x >> 6, lane = threadIdx.x & 63;
    if (lane == 0) { buf[wid][0] = s; buf[wid][1] = ss; }
    __syncthreads();
    if (threadIdx.x == 0) {
        s = buf[0][0] + buf[1][0] + buf[2][0] + buf[3][0];
        ss = buf[0][1] + buf[1][1] + buf[2][1] + buf[3][1];
        buf[0][0] = s; buf[0][1] = ss;
    }
    __syncthreads();
    s = buf[0][0]; ss = buf[0][1];

    float invC = 1.f / (float)C;
    float mu = s * invC;
    float var = ss * invC - mu * mu;
    float inv = rsqrtf(var + 1e-5f);
    const float4* gg = (const float4*)g;
    const float4* bb = (const float4*)b;
    for (int i = threadIdx.x; i < C8; i += 256) {
        uint4 raw = xr[i];
        const __hip_bfloat16* p = (const __hip_bfloat16*)&raw;
        float4 g0 = gg[2 * i], g1 = gg[2 * i + 1];
        float4 b0 = bb[2 * i], b1 = bb[2 * i + 1];
        __hip_bfloat16 t[8];
        t[0] = __float2bfloat16((__bfloat162float(p[0]) - mu) * inv * g0.x + b0.x);
        t[1] = __float2bfloat16((__bfloat162float(p[1]) - mu) * inv * g0.y + b0.y);
        t[2] = __float2bfloat16((__bfloat162float(p[2]) - mu) * inv * g0.z + b0.z);
        t[3] = __float2bfloat16((__bfloat162float(p[3]) - mu) * inv * g0.w + b0.w);
        t[4] = __float2bfloat16((__bfloat162float(p[4]) - mu) * inv * g1.x + b1.x);
        t[5] = __float2bfloat16((__bfloat162float(p[5]) - mu) * inv * g1.y + b1.y);
        t[6] = __float2bfloat16((__bfloat162float(p[6]) - mu) * inv * g1.z + b1.z);
        t[7] = __float2bfloat16((__bfloat162float(p[7]) - mu) * inv * g1.w + b1.w);
        yr[i] = *(uint4*)t;
    }
}

// ---------------- gemm128: 128x128 tile, BK=32, stride-80 LDS --------------
// C = A[M,K] @ W[N,K]^T. 256 threads = 4 waves 2x2, wave tile 64x64.
#define STR128 80   // bytes per 32-elem row (64 data + 16 pad)
__global__ __launch_bounds__(256, 3) void gemm128(
    const __hip_bfloat16* __restrict__ A,
    const __hip_bfloat16* __restrict__ W,
    const float* __restrict__ bias,
    __hip_bfloat16* __restrict__ Cout, int M, int N, int K, int act)
{
    __shared__ __align__(16) char Asl[2][128 * STR128];
    __shared__ __align__(16) char Bsl[2][128 * STR128];

    int tid = threadIdx.x;
    int wave = tid >> 6, lane = tid & 63;

    int mt, nt;
    {
        int gx = gridDim.x, gy = gridDim.y;
        int lin = blockIdx.y * gx + blockIdx.x;
        int chunk = gy >> 3;
        int xcd = lin & 7, q = lin >> 3;
        mt = xcd * chunk + (q % chunk);
        nt = q / chunk;
    }
    int bm = mt * 128, bn = nt * 128;
    int wm = wave & 1, wn = wave >> 1;
    int fm = lane & 15, quad = lane >> 4;

    int srow = lane >> 2;          // 0..15
    int skb  = (lane & 3) * 16;    // byte col 0,16,32,48

    const __hip_bfloat16* Ap = A + (long)(bm + wave * 16 + srow) * K + (lane & 3) * 8;
    const __hip_bfloat16* Bp = W + (long)(bn + wave * 16 + srow) * K + (lane & 3) * 8;
    const long a64 = (long)64 * K;

    const int nk = K / 32;
    floatx4 acc[4][4] = {};
    const int aoff = (wave * 16 + srow) * STR128 + skb;

    uint4 a0 = *(const uint4*)(Ap);
    uint4 a1 = *(const uint4*)(Ap + a64);
    uint4 b0 = *(const uint4*)(Bp);
    uint4 b1 = *(const uint4*)(Bp + a64);

    *(uint4*)(Asl[0] + aoff) = a0;
    *(uint4*)(Asl[0] + aoff + 64 * STR128) = a1;
    *(uint4*)(Bsl[0] + aoff) = b0;
    *(uint4*)(Bsl[0] + aoff + 64 * STR128) = b1;

    a0 = *(const uint4*)(Ap + 32);
    a1 = *(const uint4*)(Ap + a64 + 32);
    b0 = *(const uint4*)(Bp + 32);
    b1 = *(const uint4*)(Bp + a64 + 32);

    __syncthreads();

    for (int kt = 0; kt < nk; ++kt) {
        const int buf = kt & 1;
        const char* Ab = Asl[buf];
        const char* Bb = Bsl[buf];

        short8 bfr[4];
        #pragma unroll
        for (int j = 0; j < 4; ++j)
            bfr[j] = *(const short8*)(Bb + (wn * 64 + j * 16 + fm) * STR128 + quad * 16);
        #pragma unroll
        for (int i = 0; i < 4; ++i) {
            short8 af = *(const short8*)(Ab + (wm * 64 + i * 16 + fm) * STR128 + quad * 16);
            #pragma unroll
            for (int j = 0; j < 4; ++j)
                acc[i][j] = __builtin_amdgcn_mfma_f32_16x16x32_bf16(
                    af, bfr[j], acc[i][j], 0, 0, 0);
        }

        if (kt + 1 < nk) {
            const int nb = buf ^ 1;
            *(uint4*)(Asl[nb] + aoff) = a0;
            *(uint4*)(Asl[nb] + aoff + 64 * STR128) = a1;
            *(uint4*)(Bsl[nb] + aoff) = b0;
            *(uint4*)(Bsl[nb] + aoff + 64 * STR128) = b1;
            if (kt + 2 < nk) {
                const long o = (long)(kt + 2) * 32;
                a0 = *(const uint4*)(Ap + o);
                a1 = *(const uint4*)(Ap + a64 + o);
                b0 = *(const uint4*)(Bp + o);
                b1 = *(const uint4*)(Bp + a64 + o);
            }
        }
        __syncthreads();
    }

    int mbase = bm + wm * 64;
    int nbase = bn + wn * 64;
    #pragma unroll
    for (int i = 0; i < 4; ++i) {
        #pragma unroll
        for (int j = 0; j < 4; ++j) {
            int ncol = nbase + j * 16 + fm;
            #pragma unroll
            for (int r = 0; r < 4; ++r) {
                int mrow = mbase + i * 16 + quad * 4 + r;
                float v = acc[i][j][r];
                if (bias) v += bias[ncol];
                if (act == 1) {
                    float z = v * (1.5957691216f + 0.0713548162f * v * v);
                    v = v / (1.f + __expf(-z));
                }
                Cout[(long)mrow * N + ncol] = __float2bfloat16(v);
            }
        }
    }
}

// ---------------- gemm64: 64x64 tile, BK=64, stride-144 LDS ----------------
// C = A[M,K] @ W[N,K]^T + bias + residual. 4 waves 2x2, wave tile 32x32.
// Double-buffered, named-reg staging (4 uint4/thread), 1 barrier/64-K iter.
#define STR64 144   // bytes per 64-elem row (128 data + 16 pad)
__global__ __launch_bounds__(256, 4) void gemm64(
    const __hip_bfloat16* __restrict__ A,
    const __hip_bfloat16* __restrict__ W,
    const float* __restrict__ bias, const float* __restrict__ residual,
    float* __restrict__ Cout, int M, int N, int K)
{
    __shared__ __align__(16) char Asl[2][64 * STR64];   // 9 KB each
    __shared__ __align__(16) char Bsl[2][64 * STR64];

    int tid = threadIdx.x;
    int wave = tid >> 6, lane = tid & 63;

    int mt, nt;
    {
        int gx = gridDim.x, gy = gridDim.y;
        int lin = blockIdx.y * gx + blockIdx.x;
        int chunk = gy >> 3;
        int xcd = lin & 7, q = lin >> 3;
        mt = xcd * chunk + (q % chunk);
        nt = q / chunk;
    }
    int bm = mt * 64, bn = nt * 64;
    int wm = wave & 1, wn = wave >> 1;
    int fm = lane & 15, quad = lane >> 4;

    int r0 = tid >> 3;             // 0..31
    int c0 = tid & 7;              // 16B chunk col

    const __hip_bfloat16* Ap = A + (long)(bm + r0) * K + c0 * 8;
    const __hip_bfloat16* Bp = W + (long)(bn + r0) * K + c0 * 8;
    const long r32 = (long)32 * K;

    const int nk = K / 64;
    floatx4 acc[2][2] = {};
    const int lo = r0 * STR64 + c0 * 16;

    uint4 a0 = *(const uint4*)(Ap);
    uint4 a1 = *(const uint4*)(Ap + r32);
    uint4 b0 = *(const uint4*)(Bp);
    uint4 b1 = *(const uint4*)(Bp + r32);

    *(uint4*)(Asl[0] + lo) = a0;
    *(uint4*)(Asl[0] + lo + 32 * STR64) = a1;
    *(uint4*)(Bsl[0] + lo) = b0;
    *(uint4*)(Bsl[0] + lo + 32 * STR64) = b1;

    a0 = *(const uint4*)(Ap + 64);
    a1 = *(const uint4*)(Ap + r32 + 64);
    b0 = *(const uint4*)(Bp + 64);
    b1 = *(const uint4*)(Bp + r32 + 64);

    __syncthreads();

    for (int kt = 0; kt < nk; ++kt) {
        const int buf = kt & 1;
        const char* Ab = Asl[buf];
        const char* Bb = Bsl[buf];

        #pragma unroll
        for (int kh = 0; kh < 2; ++kh) {
            short8 bf0 = *(const short8*)(Bb + (wn * 32 + fm) * STR64 + kh * 64 + quad * 16);
            short8 bf1 = *(const short8*)(Bb + (wn * 32 + 16 + fm) * STR64 + kh * 64 + quad * 16);
            short8 af0 = *(const short8*)(Ab + (wm * 32 + fm) * STR64 + kh * 64 + quad * 16);
            short8 af1 = *(const short8*)(Ab + (wm * 32 + 16 + fm) * STR64 + kh * 64 + quad * 16);
            acc[0][0] = __builtin_amdgcn_mfma_f32_16x16x32_bf16(af0, bf0, acc[0][0], 0, 0, 0);
            acc[0][1] = __builtin_amdgcn_mfma_f32_16x16x32_bf16(af0, bf1, acc[0][1], 0, 0, 0);
            acc[1][0] = __builtin_amdgcn_mfma_f32_16x16x32_bf16(af1, bf0, acc[1][0], 0, 0, 0);
            acc[1][1] = __builtin_amdgcn_mfma_f32_16x16x32_bf16(af1, bf1, acc[1][1], 0, 0, 0);
        }

        if (kt + 1 < nk) {
            const int nb = buf ^ 1;
            *(uint4*)(Asl[nb] + lo) = a0;
            *(uint4*)(Asl[nb] + lo + 32 * STR64) = a1;
            *(uint4*)(Bsl[nb] + lo) = b0;
            *(uint4*)(Bsl[nb] + lo + 32 * STR64) = b1;
            if (kt + 2 < nk) {
                const long o = (long)(kt + 2) * 64;
                a0 = *(const uint4*)(Ap + o);
                a1 = *(const uint4*)(Ap + r32 + o);
                b0 = *(const uint4*)(Bp + o);
                b1 = *(const uint4*)(Bp + r32 + o);
            }
        }
        __syncthreads();
    }

    int mbase = bm + wm * 32;
    int nbase = bn + wn * 32;
    #pragma unroll
    for (int i = 0; i < 2; ++i) {
        #pragma unroll
        for (int j = 0; j < 2; ++j) {
            int ncol = nbase + j * 16 + fm;
            #pragma unroll
            for (int r = 0; r < 4; ++r) {
                int mrow = mbase + i * 16 + quad * 4 + r;
                float v = acc[i][j][r] + bias[ncol]
                        + residual[(long)mrow * N + ncol];
                Cout[(long)mrow * N + ncol] = v;
            }
        }
    }
}

// ---------------- MFMA flash attention, pipelined (R5, unchanged) ----------
__global__ __launch_bounds__(256) void attn_mfma(
    const __hip_bfloat16* __restrict__ qkv, __hip_bfloat16* __restrict__ o_out)
{
    __shared__ __align__(16) char Ks[2][64 * 144];
    __shared__ __align__(16) char Vt[2][64 * 144];
    __shared__ __align__(16) char Ps[4 * 16 * 144];

    const int C3 = 3 * CDIM;
    int lin = blockIdx.x;
    int xcd = lin & 7, q = lin >> 3;
    int bh = xcd * 8 + (q >> 4);
    int qt = q & 15;
    int b = bh >> 4, hh = bh & 15;
    int tid = threadIdx.x, wave = tid >> 6, lane = tid & 63;
    int l = lane & 15, quad = lane >> 4;

    const __hip_bfloat16* qrow =
        qkv + (long)(b * 1024 + qt * 64 + wave * 16 + l) * C3 + hh * DHEAD;
    short8 qf0 = *(const short8*)(qrow + quad * 8);
    short8 qf1 = *(const short8*)(qrow + 32 + quad * 8);

    char* Psw = Ps + wave * (16 * 144);

    int sc = tid & 7;
    int skl = tid >> 3;

    const __hip_bfloat16* Kbase = qkv + (long)(b * 1024) * C3 + CDIM + hh * DHEAD;
    const __hip_bfloat16* Vbase = qkv + (long)(b * 1024) * C3 + 2 * CDIM + hh * DHEAD;
    const int kpp = skl ^ (sc << 2);

    floatx4 facc[4] = {};
    float mrun = -1e30f, lrun = 0.f;

    uint4 kA0, kA1, vA0, vA1;
    uint4 kB0, kB1, vB0, vB1;

#define GKV(t, k0, k1, v0, v1) { \
    const __hip_bfloat16* Kg = Kbase + (long)((t) * 64) * C3; \
    const __hip_bfloat16* Vg = Vbase + (long)((t) * 64) * C3; \
    k0 = *(const uint4*)(Kg + (long)skl * C3 + sc * 8); \
    k1 = *(const uint4*)(Kg + (long)(skl + 32) * C3 + sc * 8); \
    v0 = *(const uint4*)(Vg + (long)(2 * skl) * C3 + sc * 8); \
    v1 = *(const uint4*)(Vg + (long)(2 * skl + 1) * C3 + sc * 8); }
#define WKV(bf, k0, k1, v0, v1) { \
    *(uint4*)(Ks[bf] + skl * 144 + sc * 16) = k0; \
    *(uint4*)(Ks[bf] + (skl + 32) * 144 + sc * 16) = k1; \
    const ushort* e0 = (const ushort*)&v0; \
    const ushort* e1 = (const ushort*)&v1; \
    _Pragma("unroll") \
    for (int j = 0; j < 8; ++j) { \
        unsigned dw = (unsigned)e0[j] | ((unsigned)e1[j] << 16); \
        *(unsigned*)(Vt[bf] + (sc * 8 + j) * 144 + kpp * 4) = dw; \
    } }

    auto compute = [&](int buf) {
        floatx4 st[4] = {};
        #pragma unroll
        for (int kb = 0; kb < 4; ++kb) {
            short8 k0 = *(const short8*)(Ks[buf] + (kb * 16 + l) * 144 + quad * 16);
            short8 k1 = *(const short8*)(Ks[buf] + (kb * 16 + l) * 144 + 64 + quad * 16);
            st[kb] = __builtin_amdgcn_mfma_f32_16x16x32_bf16(k0, qf0, st[kb], 0, 0, 0);
            st[kb] = __builtin_amdgcn_mfma_f32_16x16x32_bf16(k1, qf1, st[kb], 0, 0, 0);
        }
        float p[16];
        float tm = -1e30f;
        #pragma unroll
        for (int kb = 0; kb < 4; ++kb)
            #pragma unroll
            for (int r = 0; r < 4; ++r) {
                float s = st[kb][r] * 0.125f;
                p[kb * 4 + r] = s;
                tm = fmaxf(tm, s);
            }
        tm = fmaxf(tm, __shfl_xor(tm, 16));
        tm = fmaxf(tm, __shfl_xor(tm, 32));
        float mn = fmaxf(mrun, tm);
        float alpha = __expf(mrun - mn);
        float psum = 0.f;
        #pragma unroll
        for (int i = 0; i < 16; ++i) { p[i] = __expf(p[i] - mn); psum += p[i]; }
        psum += __shfl_xor(psum, 16);
        psum += __shfl_xor(psum, 32);
        lrun = lrun * alpha + psum;
        mrun = mn;

        #pragma unroll
        for (int kb = 0; kb < 4; ++kb) {
            __hip_bfloat16 t[4];
            #pragma unroll
            for (int r = 0; r < 4; ++r) t[r] = __float2bfloat16(p[kb * 4 + r]);
            *(uint2*)(Psw + l * 144 + kb * 32 + quad * 8) = *(const uint2*)t;
        }

        float a0 = __shfl(alpha, quad * 4 + 0);
        float a1 = __shfl(alpha, quad * 4 + 1);
        float a2 = __shfl(alpha, quad * 4 + 2);
        float a3 = __shfl(alpha, quad * 4 + 3);
        #pragma unroll
        for (int db = 0; db < 4; ++db) {
            facc[db][0] *= a0; facc[db][1] *= a1;
            facc[db][2] *= a2; facc[db][3] *= a3;
        }

        short8 pf0 = *(const short8*)(Psw + l * 144 + quad * 16);
        short8 pf1 = *(const short8*)(Psw + l * 144 + 64 + quad * 16);
        #pragma unroll
        for (int db = 0; db < 4; ++db) {
            int d = db * 16 + l;
            int o3 = (d >> 3) & 7;
            short8 v0 = *(const short8*)(Vt[buf] + d * 144 + ((quad ^ o3) << 4));
            short8 v1 = *(const short8*)(Vt[buf] + d * 144 + (((4 + quad) ^ o3) << 4));
            facc[db] = __builtin_amdgcn_mfma_f32_16x16x32_bf16(pf0, v0, facc[db], 0, 0, 0);
            facc[db] = __builtin_amdgcn_mfma_f32_16x16x32_bf16(pf1, v1, facc[db], 0, 0, 0);
        }
    };

    GKV(0, kA0, kA1, vA0, vA1);
    #pragma unroll 1
    for (int kt = 0; kt < 16; kt += 2) {
        WKV(0, kA0, kA1, vA0, vA1);
        __syncthreads();
        GKV(kt + 1, kB0, kB1, vB0, vB1);
        compute(0);
        WKV(1, kB0, kB1, vB0, vB1);
        __syncthreads();
        if (kt + 2 < 16) GKV(kt + 2, kA0, kA1, vA0, vA1);
        compute(1);
    }
#undef GKV
#undef WKV

    float il0 = 1.f / __shfl(lrun, quad * 4 + 0);
    float il1 = 1.f / __shfl(lrun, quad * 4 + 1);
    float il2 = 1.f / __shfl(lrun, quad * 4 + 2);
    float il3 = 1.f / __shfl(lrun, quad * 4 + 3);
    __hip_bfloat16* orow =
        o_out + (long)(b * 1024 + qt * 64 + wave * 16) * CDIM + hh * DHEAD;
    #pragma unroll
    for (int db = 0; db < 4; ++db) {
        int col = db * 16 + l;
        orow[(quad * 4 + 0) * CDIM + col] = __float2bfloat16(facc[db][0] * il0);
        orow[(quad * 4 + 1) * CDIM + col] = __float2bfloat16(facc[db][1] * il1);
        orow[(quad * 4 + 2) * CDIM + col] = __float2bfloat16(facc[db][2] * il2);
        orow[(quad * 4 + 3) * CDIM + col] = __float2bfloat16(facc[db][3] * il3);
    }
}

// ---------------------------------------------------------------------------
extern "C" void kernel_launch(void* const* d_in, const int* in_sizes, int n_in,
                              void* d_out, int out_size, void* d_ws, size_t ws_size,
                              hipStream_t stream)
{
    const float* x      = (const float*)d_in[0];
    const float* qkv_w  = (const float*)d_in[1];
    const float* proj_w = (const float*)d_in[2];
    const float* proj_b = (const float*)d_in[3];
    const float* fc1_w  = (const float*)d_in[4];
    const float* fc1_b  = (const float*)d_in[5];
    const float* fc2_w  = (const float*)d_in[6];
    const float* fc2_b  = (const float*)d_in[7];
    const float* ln1_g  = (const float*)d_in[8];
    const float* ln1_b  = (const float*)d_in[9];
    const float* ln2_g  = (const float*)d_in[10];
    const float* ln2_b  = (const float*)d_in[11];
    const float* lnh_g  = (const float*)d_in[12];
    const float* lnh_b  = (const float*)d_in[13];

    float* out = (float*)d_out;

    __hip_bfloat16* wsb     = (__hip_bfloat16*)d_ws;
    __hip_bfloat16* qkvw_bf = wsb;
    __hip_bfloat16* fc1w_bf = qkvw_bf + 3l * 1024 * 1024;
    __hip_bfloat16* fc2w_bf = fc1w_bf + 4l * 1024 * 1024;
    __hip_bfloat16* projw_bf= fc2w_bf + 4l * 1024 * 1024;
    __hip_bfloat16* h_bf    = projw_bf + 1l * 1024 * 1024;
    __hip_bfloat16* qkv_bf  = h_bf + 4l * 1024 * 1024;
    __hip_bfloat16* o_bf    = qkv_bf + 12l * 1024 * 1024;
    __hip_bfloat16* u_bf    = o_bf + 4l * 1024 * 1024;

    // 0. all weights fp32 -> bf16
    cvt_all<<<12288, 256, 0, stream>>>(qkv_w, fc1_w, fc2_w, proj_w, qkvw_bf);

    // 1. h = LN1(x)
    ln_f32_kernel<<<TOKENS, 256, 0, stream>>>(x, ln1_g, ln1_b, h_bf, CDIM);
    // 2. qkv = h @ qkv_w^T
    gemm128<<<dim3(3072 / 128, TOKENS / 128), 256, 0, stream>>>(
        h_bf, qkvw_bf, nullptr, qkv_bf, TOKENS, 3072, CDIM, 0);
    // 3. o = attention(qkv)
    attn_mfma<<<1024, 256, 0, stream>>>(qkv_bf, o_bf);
    // 4. out = x + o @ proj_w^T + proj_b
    gemm64<<<dim3(CDIM / 64, TOKENS / 64), 256, 0, stream>>>(
        o_bf, projw_bf, proj_b, x, out, TOKENS, CDIM, CDIM);
    // 5. h2 = LN2(out)
    ln_f32_kernel<<<TOKENS, 256, 0, stream>>>(out, ln2_g, ln2_b, h_bf, CDIM);
    // 6. u = gelu(h2 @ fc1_w^T + fc1_b)
    gemm128<<<dim3(HID / 128, TOKENS / 128), 256, 0, stream>>>(
        h_bf, fc1w_bf, fc1_b, u_bf, TOKENS, HID, CDIM, 1);
    // 7. u = LNh(u) in place
    ln_bf16_kernel<<<TOKENS, 256, 0, stream>>>(u_bf, lnh_g, lnh_b, u_bf, HID);
    // 8. out = out + u @ fc2_w^T + fc2_b
    gemm64<<<dim3(CDIM / 64, TOKENS / 64), 256, 0, stream>>>(
        u_bf, fc2w_bf, fc2_b, out, out, TOKENS, CDIM, HID);
}